// Round 3
// baseline (187.898 us; speedup 1.0000x reference)
//
#include <hip/hip_runtime.h>

#define S_LEN 4096
#define EMBD  1024
#define HEADD 64

typedef __bf16 bf16x8 __attribute__((ext_vector_type(8)));
typedef __bf16 bf16x4 __attribute__((ext_vector_type(4)));
typedef float  f32x4  __attribute__((ext_vector_type(4)));

__device__ __forceinline__ unsigned short f2bf(float f) {
  union { float f; unsigned u; } x; x.f = f;
  unsigned r = x.u + 0x7FFFu + ((x.u >> 16) & 1u);
  return (unsigned short)(r >> 16);
}

__device__ __forceinline__ bf16x8 cvt8(f32x4 a, f32x4 b) {
  union { bf16x8 v; unsigned short s[8]; } u;
#pragma unroll
  for (int j = 0; j < 4; j++) { u.s[j] = f2bf(a[j]); u.s[4 + j] = f2bf(b[j]); }
  return u.v;
}

// ---------------- Kernel 0: W transpose/convert + bias; fold scale*log2e into Q ----
__global__ void prep_w(const float* __restrict__ Wk, const float* __restrict__ bk,
                       const float* __restrict__ Wq, const float* __restrict__ bq,
                       const float* __restrict__ Wv, const float* __restrict__ bv,
                       unsigned short* __restrict__ wt, float* __restrict__ bias) {
  int n = blockIdx.x;            // 0..191 : [0,64)=K, [64,128)=Q(scaled), [128,192)=V
  int t = threadIdx.x;
  const float QSCALE = 0.125f * 1.44269504088896340736f;  // 1/sqrt(64) * log2(e)
  const float* W; const float* bsrc; int col; float s = 1.0f;
  if (n < 64)       { W = Wk; bsrc = bk; col = n; }
  else if (n < 128) { W = Wq; bsrc = bq; col = n - 64; s = QSCALE; }
  else              { W = Wv; bsrc = bv; col = n - 128; }
  for (int k = t; k < EMBD; k += 256)
    wt[n * EMBD + k] = f2bf(W[k * HEADD + col] * s);
  if (t == 0) bias[n] = bsrc[col] * s;
}

// ---------------- Kernel 1: QKV projection, fused 192 cols, k-split 2 ---------------
// grid 512 x 256 threads (4 waves): wave = (rg2, kh); 32 rows/block; X read ONCE.
// kh=0: K cols 0..511, kh=1: 512..1023; f32 partial-acc merge via LDS.
__global__ __launch_bounds__(256, 2) void proj_qkv(
    const float* __restrict__ X, const unsigned short* __restrict__ wt,
    const float* __restrict__ bias,
    unsigned short* __restrict__ qws, unsigned short* __restrict__ kws,
    unsigned short* __restrict__ vtws) {
  __shared__ float part[2][12][256];   // [rg2][nf][lane*4] f32x4 partials, 24 KB

  const int wid = threadIdx.x >> 6;
  const int lane = threadIdx.x & 63;
  const int rg2 = wid >> 1, kh = wid & 1;
  const int l15 = lane & 15, lg = lane >> 4;
  const int row = blockIdx.x * 32 + rg2 * 16 + l15;
  const float* xp = X + (size_t)row * EMBD + kh * 512 + lg * 8;
  const unsigned short* wp = wt + (size_t)l15 * EMBD + kh * 512 + lg * 8;

  f32x4 acc[12];
#pragma unroll
  for (int i = 0; i < 12; i++) acc[i] = (f32x4){0.f, 0.f, 0.f, 0.f};

  // 2-deep X prefetch (two named buffers; static indexing per rule #20)
  f32x4 xa0 = *(const f32x4*)(xp);      f32x4 xb0 = *(const f32x4*)(xp + 4);
  f32x4 xa1 = *(const f32x4*)(xp + 32); f32x4 xb1 = *(const f32x4*)(xp + 36);
#pragma unroll
  for (int s = 0; s < 16; s += 2) {
    bf16x8 a0 = cvt8(xa0, xb0);
    if (s + 2 < 16) {
      xa0 = *(const f32x4*)(xp + (s + 2) * 32);
      xb0 = *(const f32x4*)(xp + (s + 2) * 32 + 4);
    }
#pragma unroll
    for (int nf = 0; nf < 12; nf++) {
      bf16x8 bf = *(const bf16x8*)(wp + (size_t)nf * 16 * EMBD + s * 32);
      acc[nf] = __builtin_amdgcn_mfma_f32_16x16x32_bf16(a0, bf, acc[nf], 0, 0, 0);
    }
    bf16x8 a1 = cvt8(xa1, xb1);
    if (s + 3 < 16) {
      xa1 = *(const f32x4*)(xp + (s + 3) * 32);
      xb1 = *(const f32x4*)(xp + (s + 3) * 32 + 4);
    }
#pragma unroll
    for (int nf = 0; nf < 12; nf++) {
      bf16x8 bf = *(const bf16x8*)(wp + (size_t)nf * 16 * EMBD + (s + 1) * 32);
      acc[nf] = __builtin_amdgcn_mfma_f32_16x16x32_bf16(a1, bf, acc[nf], 0, 0, 0);
    }
  }

  if (kh == 1) {
#pragma unroll
    for (int nf = 0; nf < 12; nf++)
      *(f32x4*)&part[rg2][nf][lane * 4] = acc[nf];
  }
  __syncthreads();
  if (kh == 0) {
    const int crow0 = blockIdx.x * 32 + rg2 * 16 + lg * 4;
#pragma unroll
    for (int nf = 0; nf < 12; nf++) {
      const f32x4 other = *(const f32x4*)&part[rg2][nf][lane * 4];
      const int n = nf * 16 + l15;
      const float bs = bias[n];
      if (nf < 8) {
        unsigned short* dst = (nf < 4) ? kws : qws;
        const int nn = n & 63;
#pragma unroll
        for (int i = 0; i < 4; i++)
          dst[(size_t)(crow0 + i) * HEADD + nn] = f2bf(acc[nf][i] + other[i] + bs);
      } else {
        const int d = n - 128;
        const int bb = crow0 >> 12, sr = crow0 & 4095;
        union { unsigned long long pk; unsigned short s[4]; } u;
#pragma unroll
        for (int i = 0; i < 4; i++) u.s[i] = f2bf(acc[nf][i] + other[i] + bs);
        *(unsigned long long*)&vtws[((size_t)bb * HEADD + d) * S_LEN + sr] = u.pk;
      }
    }
  }
}

// ---------------- Kernel 2: causal flash attention, in-block kv-split 4 -------------
// grid 1024 (4 b x 256 q-groups) x 256 threads (4 waves = 4 kv-splits).
// bitrev qt mapping -> any 2^k-strided block subset has near-equal work.
// Defer-max softmax: common path has ZERO cross-lane ops (l kept lane-partial).
__global__ __launch_bounds__(256, 4) void attn(
    const unsigned short* __restrict__ qws,
    const unsigned short* __restrict__ kws,
    const unsigned short* __restrict__ vtws,
    float* __restrict__ out) {
  __shared__ unsigned short pl[4][16][72];   // per-wave P bounce (wave-private)
  __shared__ float obuf[3][4][16][17];       // partials from waves 1..3
  __shared__ float mbuf[4][16], lbuf[4][16];

  const int w = threadIdx.x >> 6;
  const int lane = threadIdx.x & 63;
  const int l15 = lane & 15, lg = lane >> 4;

  const int b = blockIdx.x & 3;
  const int idx2 = blockIdx.x >> 2;
  const int qt = (int)(__brev((unsigned)idx2) >> 24);   // 8-bit bit-reverse
  const int qbase = qt * 16;
  const int tl = qt >> 2;                    // diagonal kv-tile index

  const unsigned short* qp = qws + ((size_t)b * S_LEN + qbase + l15) * HEADD + lg * 8;
  const bf16x8 bq0 = *(const bf16x8*)qp;
  const bf16x8 bq1 = *(const bf16x8*)(qp + 32);

  const unsigned short* kb = kws + (size_t)b * S_LEN * HEADD;
  const unsigned short* vb = vtws + (size_t)b * HEADD * S_LEN;

  f32x4 o[4];
#pragma unroll
  for (int nd = 0; nd < 4; nd++) o[nd] = (f32x4){0.f, 0.f, 0.f, 0.f};
  float m = -3.0e38f, l = 0.f;

  for (int t = w; t <= tl; t += 4) {
    // K(t) and V(t) issued together; V consumed ~300cy later (after S+softmax)
    const unsigned short* kt = kb + ((size_t)t * 64 + l15) * HEADD + lg * 8;
    bf16x8 k0[4], k1[4];
#pragma unroll
    for (int nf = 0; nf < 4; nf++) {
      k0[nf] = *(const bf16x8*)(kt + (size_t)nf * 16 * HEADD);
      k1[nf] = *(const bf16x8*)(kt + (size_t)nf * 16 * HEADD + 32);
    }
    const unsigned short* vt = vb + (size_t)l15 * S_LEN + t * 64 + lg * 8;
    bf16x8 v0[4], v1[4];
#pragma unroll
    for (int nd = 0; nd < 4; nd++) {
      v0[nd] = *(const bf16x8*)(vt + (size_t)nd * 16 * S_LEN);
      v1[nd] = *(const bf16x8*)(vt + (size_t)nd * 16 * S_LEN + 32);
    }
    // S^T = K Q^T : rows kv, cols q (q = l15 is lane-local)
    f32x4 sc[4];
#pragma unroll
    for (int nf = 0; nf < 4; nf++) {
      f32x4 z = (f32x4){0.f, 0.f, 0.f, 0.f};
      z = __builtin_amdgcn_mfma_f32_16x16x32_bf16(k0[nf], bq0, z, 0, 0, 0);
      sc[nf] = __builtin_amdgcn_mfma_f32_16x16x32_bf16(k1[nf], bq1, z, 0, 0, 0);
    }
    if (t == tl) {
      const int qa = qbase + l15;
#pragma unroll
      for (int nf = 0; nf < 4; nf++)
#pragma unroll
        for (int i = 0; i < 4; i++)
          if (t * 64 + nf * 16 + lg * 4 + i > qa) sc[nf][i] = -1.0e30f;
    }
    // defer-max online softmax (T13): common path = no cross-lane ops
    float pm = sc[0][0];
#pragma unroll
    for (int nf = 0; nf < 4; nf++)
#pragma unroll
      for (int i = 0; i < 4; i++) pm = fmaxf(pm, sc[nf][i]);
    if (!__all(pm <= m + 8.0f)) {
      float mx = fmaxf(pm, __shfl_xor(pm, 16));
      mx = fmaxf(mx, __shfl_xor(mx, 32));
      const float mn = fmaxf(m, mx);
      const float al = __builtin_amdgcn_exp2f(m - mn);
      m = mn;
      l *= al;
      float alr[4];
#pragma unroll
      for (int i = 0; i < 4; i++) alr[i] = __shfl(al, lg * 4 + i);
#pragma unroll
      for (int nd = 0; nd < 4; nd++)
#pragma unroll
        for (int i = 0; i < 4; i++) o[nd][i] *= alr[i];
    }
    float rs = 0.f;
#pragma unroll
    for (int nf = 0; nf < 4; nf++)
#pragma unroll
      for (int i = 0; i < 4; i++) {
        const float p = __builtin_amdgcn_exp2f(sc[nf][i] - m);
        rs += p;
        sc[nf][i] = p;
      }
    l += rs;                                 // lane-partial l (reduced once at end)
    // P -> LDS (wave-private re-layout for PV A-frag)
#pragma unroll
    for (int nf = 0; nf < 4; nf++) {
      union { bf16x4 v; unsigned short s[4]; } u;
#pragma unroll
      for (int i = 0; i < 4; i++) u.s[i] = f2bf(sc[nf][i]);
      *(bf16x4*)&pl[w][l15][nf * 16 + lg * 4] = u.v;
    }
    const bf16x8 ap0 = *(const bf16x8*)&pl[w][l15][lg * 8];
    const bf16x8 ap1 = *(const bf16x8*)&pl[w][l15][32 + lg * 8];
#pragma unroll
    for (int nd = 0; nd < 4; nd++) {
      f32x4 oo = __builtin_amdgcn_mfma_f32_16x16x32_bf16(ap0, v0[nd], o[nd], 0, 0, 0);
      o[nd] = __builtin_amdgcn_mfma_f32_16x16x32_bf16(ap1, v1[nd], oo, 0, 0, 0);
    }
  }

  // finalize lane-partial l, publish partials
  l += __shfl_xor(l, 16);
  l += __shfl_xor(l, 32);
  if (lane < 16) { mbuf[w][lane] = m; lbuf[w][lane] = l; }
  if (w > 0) {
#pragma unroll
    for (int nd = 0; nd < 4; nd++)
#pragma unroll
      for (int i = 0; i < 4; i++) obuf[w - 1][nd][lg * 4 + i][l15] = o[nd][i];
  }
  __syncthreads();
  if (w == 0) {
#pragma unroll
    for (int i = 0; i < 4; i++) {
      const int r = lg * 4 + i;
      const float m0 = mbuf[0][r], m1 = mbuf[1][r], m2 = mbuf[2][r], m3 = mbuf[3][r];
      const float M = fmaxf(fmaxf(m0, m1), fmaxf(m2, m3));
      const float a0 = __builtin_amdgcn_exp2f(m0 - M);
      const float a1 = __builtin_amdgcn_exp2f(m1 - M);
      const float a2 = __builtin_amdgcn_exp2f(m2 - M);
      const float a3 = __builtin_amdgcn_exp2f(m3 - M);
      const float L = a0 * lbuf[0][r] + a1 * lbuf[1][r] + a2 * lbuf[2][r] + a3 * lbuf[3][r];
      const float iL = 1.0f / L;
#pragma unroll
      for (int nd = 0; nd < 4; nd++) {
        const float val = (o[nd][i] * a0 + obuf[0][nd][r][l15] * a1 +
                           obuf[1][nd][r][l15] * a2 + obuf[2][nd][r][l15] * a3) * iL;
        out[((size_t)b * S_LEN + qbase + r) * HEADD + nd * 16 + l15] = val;
      }
    }
  }
}

extern "C" void kernel_launch(void* const* d_in, const int* in_sizes, int n_in,
                              void* d_out, int out_size, void* d_ws, size_t ws_size,
                              hipStream_t stream) {
  const float* X  = (const float*)d_in[0];
  const float* Wk = (const float*)d_in[1];
  const float* bk = (const float*)d_in[2];
  const float* Wq = (const float*)d_in[3];
  const float* bq = (const float*)d_in[4];
  const float* Wv = (const float*)d_in[5];
  const float* bv = (const float*)d_in[6];
  float* out = (float*)d_out;

  char* ws = (char*)d_ws;
  unsigned short* kws  = (unsigned short*)(ws);                      // 2 MB
  unsigned short* qws  = (unsigned short*)(ws + (2u << 20));         // 2 MB
  unsigned short* vtws = (unsigned short*)(ws + (4u << 20));         // 2 MB (transposed)
  unsigned short* wt   = (unsigned short*)(ws + (6u << 20));         // 384 KB
  float*          bias = (float*)(ws + (6u << 20) + (512u << 10));   // 768 B

  prep_w<<<dim3(192), dim3(256), 0, stream>>>(Wk, bk, Wq, bq, Wv, bv, wt, bias);
  proj_qkv<<<dim3(512), dim3(256), 0, stream>>>(X, wt, bias, qws, kws, vtws);
  attn<<<dim3(1024), dim3(256), 0, stream>>>(qws, kws, vtws, out);
}

// Round 4
// 144.358 us; speedup vs baseline: 1.3016x; 1.3016x over previous
//
#include <hip/hip_runtime.h>

#define S_LEN 4096
#define EMBD  1024
#define HEADD 64

typedef __bf16 bf16x8 __attribute__((ext_vector_type(8)));
typedef __bf16 bf16x4 __attribute__((ext_vector_type(4)));
typedef float  f32x4  __attribute__((ext_vector_type(4)));

__device__ __forceinline__ unsigned short f2bf(float f) {
  union { float f; unsigned u; } x; x.f = f;
  unsigned r = x.u + 0x7FFFu + ((x.u >> 16) & 1u);
  return (unsigned short)(r >> 16);
}

// ---------------- Kernel 0: W transpose/convert + bias; fold scale*log2e into Q ----
__global__ void prep_w(const float* __restrict__ Wk, const float* __restrict__ bk,
                       const float* __restrict__ Wq, const float* __restrict__ bq,
                       const float* __restrict__ Wv, const float* __restrict__ bv,
                       unsigned short* __restrict__ wt, float* __restrict__ bias) {
  int n = blockIdx.x;            // 0..191 : [0,64)=K, [64,128)=Q(scaled), [128,192)=V
  int t = threadIdx.x;
  const float QSCALE = 0.125f * 1.44269504088896340736f;  // 1/sqrt(64) * log2(e)
  const float* W; const float* bsrc; int col; float s = 1.0f;
  if (n < 64)       { W = Wk; bsrc = bk; col = n; }
  else if (n < 128) { W = Wq; bsrc = bq; col = n - 64; s = QSCALE; }
  else              { W = Wv; bsrc = bv; col = n - 128; }
  for (int k = t; k < EMBD; k += 256)
    wt[n * EMBD + k] = f2bf(W[k * HEADD + col] * s);
  if (t == 0) bias[n] = bsrc[col] * s;
}

// ---------------- Kernel 0b: X f32 -> bf16, pure streaming ------------------------
// 16.78M elems; thread handles 8/iter, 4 iters. 64 MB read + 32 MB write.
__global__ __launch_bounds__(256) void xcvt(const float* __restrict__ X,
                                            unsigned short* __restrict__ xb) {
  const size_t nthr = (size_t)gridDim.x * 256;
  size_t i = (size_t)blockIdx.x * 256 + threadIdx.x;
  const size_t nvec = (size_t)4 * S_LEN * EMBD / 8;
#pragma unroll 4
  for (; i < nvec; i += nthr) {
    f32x4 a = *(const f32x4*)(X + i * 8);
    f32x4 b = *(const f32x4*)(X + i * 8 + 4);
    union { bf16x8 v; unsigned short s[8]; } u;
#pragma unroll
    for (int j = 0; j < 4; j++) { u.s[j] = f2bf(a[j]); u.s[4 + j] = f2bf(b[j]); }
    *(bf16x8*)(xb + i * 8) = u.v;
  }
}

// ---------------- Kernel 1: QKV projection from bf16 X, k-split 2 -------------------
// grid 512 x 256 threads (4 waves): wave = (rg2, kh); 32 rows/block.
__global__ __launch_bounds__(256, 2) void proj_qkv(
    const unsigned short* __restrict__ xb, const unsigned short* __restrict__ wt,
    const float* __restrict__ bias,
    unsigned short* __restrict__ qws, unsigned short* __restrict__ kws,
    unsigned short* __restrict__ vtws) {
  __shared__ float part[2][12][256];   // [rg2][nf][lane*4] f32x4 partials, 24 KB

  const int wid = threadIdx.x >> 6;
  const int lane = threadIdx.x & 63;
  const int rg2 = wid >> 1, kh = wid & 1;
  const int l15 = lane & 15, lg = lane >> 4;
  const int row = blockIdx.x * 32 + rg2 * 16 + l15;
  const unsigned short* xp = xb + (size_t)row * EMBD + kh * 512 + lg * 8;
  const unsigned short* wp = wt + (size_t)l15 * EMBD + kh * 512 + lg * 8;

  f32x4 acc[12];
#pragma unroll
  for (int i = 0; i < 12; i++) acc[i] = (f32x4){0.f, 0.f, 0.f, 0.f};

  // 4-deep A prefetch (named bufs, static indexing)
  bf16x8 a0 = *(const bf16x8*)(xp);
  bf16x8 a1 = *(const bf16x8*)(xp + 32);
  bf16x8 a2 = *(const bf16x8*)(xp + 64);
  bf16x8 a3 = *(const bf16x8*)(xp + 96);
#pragma unroll
  for (int s = 0; s < 16; s += 4) {
#pragma unroll
    for (int nf = 0; nf < 12; nf++)
      acc[nf] = __builtin_amdgcn_mfma_f32_16x16x32_bf16(
          a0, *(const bf16x8*)(wp + (size_t)nf * 16 * EMBD + s * 32), acc[nf], 0, 0, 0);
    if (s + 4 < 16) a0 = *(const bf16x8*)(xp + (s + 4) * 32);
#pragma unroll
    for (int nf = 0; nf < 12; nf++)
      acc[nf] = __builtin_amdgcn_mfma_f32_16x16x32_bf16(
          a1, *(const bf16x8*)(wp + (size_t)nf * 16 * EMBD + (s + 1) * 32), acc[nf], 0, 0, 0);
    if (s + 5 < 16) a1 = *(const bf16x8*)(xp + (s + 5) * 32);
#pragma unroll
    for (int nf = 0; nf < 12; nf++)
      acc[nf] = __builtin_amdgcn_mfma_f32_16x16x32_bf16(
          a2, *(const bf16x8*)(wp + (size_t)nf * 16 * EMBD + (s + 2) * 32), acc[nf], 0, 0, 0);
    if (s + 6 < 16) a2 = *(const bf16x8*)(xp + (s + 6) * 32);
#pragma unroll
    for (int nf = 0; nf < 12; nf++)
      acc[nf] = __builtin_amdgcn_mfma_f32_16x16x32_bf16(
          a3, *(const bf16x8*)(wp + (size_t)nf * 16 * EMBD + (s + 3) * 32), acc[nf], 0, 0, 0);
    if (s + 7 < 16) a3 = *(const bf16x8*)(xp + (s + 7) * 32);
  }

  if (kh == 1) {
#pragma unroll
    for (int nf = 0; nf < 12; nf++)
      *(f32x4*)&part[rg2][nf][lane * 4] = acc[nf];
  }
  __syncthreads();
  if (kh == 0) {
    const int crow0 = blockIdx.x * 32 + rg2 * 16 + lg * 4;
#pragma unroll
    for (int nf = 0; nf < 12; nf++) {
      const f32x4 other = *(const f32x4*)&part[rg2][nf][lane * 4];
      const int n = nf * 16 + l15;
      const float bs = bias[n];
      if (nf < 8) {
        unsigned short* dst = (nf < 4) ? kws : qws;
        const int nn = n & 63;
#pragma unroll
        for (int i = 0; i < 4; i++)
          dst[(size_t)(crow0 + i) * HEADD + nn] = f2bf(acc[nf][i] + other[i] + bs);
      } else {
        const int d = n - 128;
        const int bb = crow0 >> 12, sr = crow0 & 4095;
        union { unsigned long long pk; unsigned short s[4]; } u;
#pragma unroll
        for (int i = 0; i < 4; i++) u.s[i] = f2bf(acc[nf][i] + other[i] + bs);
        *(unsigned long long*)&vtws[((size_t)bb * HEADD + d) * S_LEN + sr] = u.pk;
      }
    }
  }
}

// ---------------- Kernel 2: causal flash attention ---------------------------------
// 512 blocks x 256 thr (4 waves, kv-split-4). Each block: TWO q-groups (heavy then
// light: qt = 255-j2, then j2) -> uniform 65-tile work per block; all 512 blocks
// co-resident (2/CU) -> no dispatch imbalance. K/V software-pipelined one tile ahead.
__global__ __launch_bounds__(256, 2) void attn(
    const unsigned short* __restrict__ qws,
    const unsigned short* __restrict__ kws,
    const unsigned short* __restrict__ vtws,
    float* __restrict__ out) {
  __shared__ unsigned short pl[4][16][72];   // per-wave P bounce (wave-private)
  __shared__ float obuf[3][4][16][17];       // partials from waves 1..3
  __shared__ float mbuf[4][16], lbuf[4][16];

  const int w = threadIdx.x >> 6;
  const int lane = threadIdx.x & 63;
  const int l15 = lane & 15, lg = lane >> 4;

  const int b = blockIdx.x & 3;
  const int j2 = blockIdx.x >> 2;            // 0..127
  const unsigned short* kb = kws + (size_t)b * S_LEN * HEADD;
  const unsigned short* vb = vtws + (size_t)b * HEADD * S_LEN;

#pragma unroll 1
  for (int p = 0; p < 2; p++) {
    const int qt = p ? j2 : 255 - j2;
    const int qbase = qt * 16;
    const int tl = qt >> 2;                  // diagonal kv-tile index

    const unsigned short* qp = qws + ((size_t)b * S_LEN + qbase + l15) * HEADD + lg * 8;
    const bf16x8 bq0 = *(const bf16x8*)qp;
    const bf16x8 bq1 = *(const bf16x8*)(qp + 32);

    f32x4 o[4];
#pragma unroll
    for (int nd = 0; nd < 4; nd++) o[nd] = (f32x4){0.f, 0.f, 0.f, 0.f};
    float m = -3.0e38f, l = 0.f;

    if (w <= tl) {
      bf16x8 k0[4], k1[4], v0[4], v1[4];
      {
        const unsigned short* kt = kb + ((size_t)w * 64 + l15) * HEADD + lg * 8;
        const unsigned short* vt = vb + (size_t)l15 * S_LEN + w * 64 + lg * 8;
#pragma unroll
        for (int nf = 0; nf < 4; nf++) {
          k0[nf] = *(const bf16x8*)(kt + (size_t)nf * 16 * HEADD);
          k1[nf] = *(const bf16x8*)(kt + (size_t)nf * 16 * HEADD + 32);
          v0[nf] = *(const bf16x8*)(vt + (size_t)nf * 16 * S_LEN);
          v1[nf] = *(const bf16x8*)(vt + (size_t)nf * 16 * S_LEN + 32);
        }
      }
      for (int t = w; t <= tl; t += 4) {
        // S^T = K Q^T : rows kv, cols q (q = l15 lane-local)
        f32x4 sc[4];
#pragma unroll
        for (int nf = 0; nf < 4; nf++) {
          f32x4 z = (f32x4){0.f, 0.f, 0.f, 0.f};
          z = __builtin_amdgcn_mfma_f32_16x16x32_bf16(k0[nf], bq0, z, 0, 0, 0);
          sc[nf] = __builtin_amdgcn_mfma_f32_16x16x32_bf16(k1[nf], bq1, z, 0, 0, 0);
        }
        // issue next tile's K,V immediately (full-tile latency cover)
        const bool hn = (t + 4) <= tl;
        bf16x8 nk0[4], nk1[4], nv0[4], nv1[4];
        if (hn) {
          const unsigned short* kt = kb + ((size_t)(t + 4) * 64 + l15) * HEADD + lg * 8;
          const unsigned short* vt = vb + (size_t)l15 * S_LEN + (t + 4) * 64 + lg * 8;
#pragma unroll
          for (int nf = 0; nf < 4; nf++) {
            nk0[nf] = *(const bf16x8*)(kt + (size_t)nf * 16 * HEADD);
            nk1[nf] = *(const bf16x8*)(kt + (size_t)nf * 16 * HEADD + 32);
            nv0[nf] = *(const bf16x8*)(vt + (size_t)nf * 16 * S_LEN);
            nv1[nf] = *(const bf16x8*)(vt + (size_t)nf * 16 * S_LEN + 32);
          }
        }
        if (t == tl) {
          const int qa = qbase + l15;
#pragma unroll
          for (int nf = 0; nf < 4; nf++)
#pragma unroll
            for (int i = 0; i < 4; i++)
              if (t * 64 + nf * 16 + lg * 4 + i > qa) sc[nf][i] = -1.0e30f;
        }
        // defer-max online softmax: common path has zero cross-lane ops
        float pm = sc[0][0];
#pragma unroll
        for (int nf = 0; nf < 4; nf++)
#pragma unroll
          for (int i = 0; i < 4; i++) pm = fmaxf(pm, sc[nf][i]);
        if (!__all(pm <= m + 8.0f)) {
          float mx = fmaxf(pm, __shfl_xor(pm, 16));
          mx = fmaxf(mx, __shfl_xor(mx, 32));
          const float mn = fmaxf(m, mx);
          const float al = __builtin_amdgcn_exp2f(m - mn);
          m = mn;
          l *= al;
          float alr[4];
#pragma unroll
          for (int i = 0; i < 4; i++) alr[i] = __shfl(al, lg * 4 + i);
#pragma unroll
          for (int nd = 0; nd < 4; nd++)
#pragma unroll
            for (int i = 0; i < 4; i++) o[nd][i] *= alr[i];
        }
        float rs = 0.f;
#pragma unroll
        for (int nf = 0; nf < 4; nf++)
#pragma unroll
          for (int i = 0; i < 4; i++) {
            const float pv = __builtin_amdgcn_exp2f(sc[nf][i] - m);
            rs += pv;
            sc[nf][i] = pv;
          }
        l += rs;                             // lane-partial l
        // P -> LDS (wave-private re-layout for PV A-frag)
#pragma unroll
        for (int nf = 0; nf < 4; nf++) {
          union { bf16x4 v; unsigned short s[4]; } u;
#pragma unroll
          for (int i = 0; i < 4; i++) u.s[i] = f2bf(sc[nf][i]);
          *(bf16x4*)&pl[w][l15][nf * 16 + lg * 4] = u.v;
        }
        const bf16x8 ap0 = *(const bf16x8*)&pl[w][l15][lg * 8];
        const bf16x8 ap1 = *(const bf16x8*)&pl[w][l15][32 + lg * 8];
#pragma unroll
        for (int nd = 0; nd < 4; nd++) {
          f32x4 oo = __builtin_amdgcn_mfma_f32_16x16x32_bf16(ap0, v0[nd], o[nd], 0, 0, 0);
          o[nd] = __builtin_amdgcn_mfma_f32_16x16x32_bf16(ap1, v1[nd], oo, 0, 0, 0);
        }
        if (hn) {
#pragma unroll
          for (int nf = 0; nf < 4; nf++) {
            k0[nf] = nk0[nf]; k1[nf] = nk1[nf];
            v0[nf] = nv0[nf]; v1[nf] = nv1[nf];
          }
        }
      }
    }

    // finalize lane-partial l, publish partials
    l += __shfl_xor(l, 16);
    l += __shfl_xor(l, 32);
    if (lane < 16) { mbuf[w][lane] = m; lbuf[w][lane] = l; }
    if (w > 0) {
#pragma unroll
      for (int nd = 0; nd < 4; nd++)
#pragma unroll
        for (int i = 0; i < 4; i++) obuf[w - 1][nd][lg * 4 + i][l15] = o[nd][i];
    }
    __syncthreads();
    if (w == 0) {
#pragma unroll
      for (int i = 0; i < 4; i++) {
        const int r = lg * 4 + i;
        const float m0 = mbuf[0][r], m1 = mbuf[1][r], m2 = mbuf[2][r], m3 = mbuf[3][r];
        const float M = fmaxf(fmaxf(m0, m1), fmaxf(m2, m3));
        const float a0 = __builtin_amdgcn_exp2f(m0 - M);
        const float a1 = __builtin_amdgcn_exp2f(m1 - M);
        const float a2 = __builtin_amdgcn_exp2f(m2 - M);
        const float a3 = __builtin_amdgcn_exp2f(m3 - M);
        const float L = a0 * lbuf[0][r] + a1 * lbuf[1][r] + a2 * lbuf[2][r] + a3 * lbuf[3][r];
        const float iL = 1.0f / L;
#pragma unroll
        for (int nd = 0; nd < 4; nd++) {
          const float val = (o[nd][i] * a0 + obuf[0][nd][r][l15] * a1 +
                             obuf[1][nd][r][l15] * a2 + obuf[2][nd][r][l15] * a3) * iL;
          out[((size_t)b * S_LEN + qbase + r) * HEADD + nd * 16 + l15] = val;
        }
      }
    }
    __syncthreads();   // obuf/mbuf safe to reuse in next phase
  }
}

extern "C" void kernel_launch(void* const* d_in, const int* in_sizes, int n_in,
                              void* d_out, int out_size, void* d_ws, size_t ws_size,
                              hipStream_t stream) {
  const float* X  = (const float*)d_in[0];
  const float* Wk = (const float*)d_in[1];
  const float* bk = (const float*)d_in[2];
  const float* Wq = (const float*)d_in[3];
  const float* bq = (const float*)d_in[4];
  const float* Wv = (const float*)d_in[5];
  const float* bv = (const float*)d_in[6];
  float* out = (float*)d_out;

  char* ws = (char*)d_ws;
  unsigned short* kws  = (unsigned short*)(ws);                      // 2 MB
  unsigned short* qws  = (unsigned short*)(ws + (2u << 20));         // 2 MB
  unsigned short* vtws = (unsigned short*)(ws + (4u << 20));         // 2 MB (transposed)
  unsigned short* wt   = (unsigned short*)(ws + (6u << 20));         // 384 KB
  float*          bias = (float*)(ws + (6u << 20) + (512u << 10));   // 768 B
  unsigned short* xb   = (unsigned short*)(ws + (7u << 20));         // 32 MB bf16 X

  prep_w<<<dim3(192), dim3(256), 0, stream>>>(Wk, bk, Wq, bq, Wv, bv, wt, bias);
  xcvt<<<dim3(2048), dim3(256), 0, stream>>>(X, xb);
  proj_qkv<<<dim3(512), dim3(256), 0, stream>>>(xb, wt, bias, qws, kws, vtws);
  attn<<<dim3(512), dim3(256), 0, stream>>>(qws, kws, vtws, out);
}

// Round 5
// 125.391 us; speedup vs baseline: 1.4985x; 1.1513x over previous
//
#include <hip/hip_runtime.h>

#define S_LEN 4096
#define EMBD  1024
#define HEADD 64

typedef __bf16 bf16x8 __attribute__((ext_vector_type(8)));
typedef float  f32x4  __attribute__((ext_vector_type(4)));

__device__ __forceinline__ unsigned short f2bf(float f) {
  union { float f; unsigned u; } x; x.f = f;
  unsigned r = x.u + 0x7FFFu + ((x.u >> 16) & 1u);
  return (unsigned short)(r >> 16);
}

__device__ __forceinline__ bf16x8 cvt8(f32x4 a, f32x4 b) {
  union { bf16x8 v; unsigned short s[8]; } u;
#pragma unroll
  for (int j = 0; j < 4; j++) { u.s[j] = f2bf(a[j]); u.s[4 + j] = f2bf(b[j]); }
  return u.v;
}

__device__ __forceinline__ unsigned fbits(float f) {
  union { float f; unsigned u; } x; x.f = f; return x.u;
}

// ---------------- Kernel 0: W transpose/convert + bias; fold scale*log2e into Q ----
__global__ void prep_w(const float* __restrict__ Wk, const float* __restrict__ bk,
                       const float* __restrict__ Wq, const float* __restrict__ bq,
                       const float* __restrict__ Wv, const float* __restrict__ bv,
                       unsigned short* __restrict__ wt, float* __restrict__ bias) {
  int n = blockIdx.x;            // 0..191 : [0,64)=K, [64,128)=Q(scaled), [128,192)=V
  int t = threadIdx.x;
  const float QSCALE = 0.125f * 1.44269504088896340736f;  // 1/sqrt(64) * log2(e)
  const float* W; const float* bsrc; int col; float s = 1.0f;
  if (n < 64)       { W = Wk; bsrc = bk; col = n; }
  else if (n < 128) { W = Wq; bsrc = bq; col = n - 64; s = QSCALE; }
  else              { W = Wv; bsrc = bv; col = n - 128; }
  for (int k = t; k < EMBD; k += 256)
    wt[n * EMBD + k] = f2bf(W[k * HEADD + col] * s);
  if (t == 0) bias[n] = bsrc[col] * s;
}

// ---------------- Kernel 1: QKV projection, f32 X, deep-pipelined ------------------
// 512 blocks x 128 thr (2 waves x 16 rows = 32 rows/block). Full N=192, K=1024.
// W-frags ping-pong 1 K-step ahead (96 regs); X f32 3-deep rotation (24 regs).
__global__ __launch_bounds__(128, 2) void proj_qkv(
    const float* __restrict__ X, const unsigned short* __restrict__ wt,
    const float* __restrict__ bias,
    unsigned short* __restrict__ qws, unsigned short* __restrict__ kws,
    unsigned short* __restrict__ vtws) {
  const int wid = threadIdx.x >> 6;
  const int lane = threadIdx.x & 63;
  const int l15 = lane & 15, lg = lane >> 4;
  const int row = blockIdx.x * 32 + wid * 16 + l15;
  const float* xp = X + (size_t)row * EMBD + lg * 8;
  const unsigned short* wp = wt + (size_t)l15 * EMBD + lg * 8;

  f32x4 acc[12];
#pragma unroll
  for (int i = 0; i < 12; i++) acc[i] = (f32x4){0.f, 0.f, 0.f, 0.f};

  f32x4 xa[3], xb[3];
#pragma unroll
  for (int i = 0; i < 3; i++) {
    xa[i] = *(const f32x4*)(xp + i * 32);
    xb[i] = *(const f32x4*)(xp + i * 32 + 4);
  }
  bf16x8 wf[2][12];
#pragma unroll
  for (int nf = 0; nf < 12; nf++)
    wf[0][nf] = *(const bf16x8*)(wp + (size_t)nf * 16 * EMBD);

#pragma unroll
  for (int s = 0; s < 32; s++) {
    const int cur = s % 3, wc = s & 1;       // compile-time after unroll
    if (s + 1 < 32) {
#pragma unroll
      for (int nf = 0; nf < 12; nf++)
        wf[wc ^ 1][nf] = *(const bf16x8*)(wp + (size_t)nf * 16 * EMBD + (s + 1) * 32);
    }
    bf16x8 a = cvt8(xa[cur], xb[cur]);
    if (s + 3 < 32) {
      xa[cur] = *(const f32x4*)(xp + (s + 3) * 32);
      xb[cur] = *(const f32x4*)(xp + (s + 3) * 32 + 4);
    }
#pragma unroll
    for (int nf = 0; nf < 12; nf++)
      acc[nf] = __builtin_amdgcn_mfma_f32_16x16x32_bf16(a, wf[wc][nf], acc[nf], 0, 0, 0);
  }

  const int crow0 = blockIdx.x * 32 + wid * 16 + lg * 4;
#pragma unroll
  for (int nf = 0; nf < 12; nf++) {
    const int n = nf * 16 + l15;
    const float bs = bias[n];
    if (nf < 8) {
      unsigned short* dst = (nf < 4) ? kws : qws;
      const int nn = n & 63;
#pragma unroll
      for (int i = 0; i < 4; i++)
        dst[(size_t)(crow0 + i) * HEADD + nn] = f2bf(acc[nf][i] + bs);
    } else {
      const int d = n - 128;
      const int bb = crow0 >> 12, sr = crow0 & 4095;
      union { unsigned long long pk; unsigned short s[4]; } u;
#pragma unroll
      for (int i = 0; i < 4; i++) u.s[i] = f2bf(acc[nf][i] + bs);
      *(unsigned long long*)&vtws[((size_t)bb * HEADD + d) * S_LEN + sr] = u.pk;
    }
  }
}

// ---------------- Kernel 2: causal flash attention ---------------------------------
// 512 blocks x 256 thr (4 waves, kv-split-4), 2 blocks/CU, paired heavy+light
// q-groups per block. K/V double-buffered in NAMED register sets (ping-pong, no
// copies) so the pipeline survives register allocation. P packed via v_perm.
__global__ __launch_bounds__(256, 2) void attn(
    const unsigned short* __restrict__ qws,
    const unsigned short* __restrict__ kws,
    const unsigned short* __restrict__ vtws,
    float* __restrict__ out) {
  __shared__ unsigned short pl[4][16][72];   // per-wave P bounce (wave-private)
  __shared__ float obuf[3][4][16][17];       // partials from waves 1..3
  __shared__ float mbuf[4][16], lbuf[4][16];

  const int w = threadIdx.x >> 6;
  const int lane = threadIdx.x & 63;
  const int l15 = lane & 15, lg = lane >> 4;

  const int b = blockIdx.x & 3;
  const int j2 = blockIdx.x >> 2;            // 0..127
  const unsigned short* kb = kws + (size_t)b * S_LEN * HEADD;
  const unsigned short* vb = vtws + (size_t)b * HEADD * S_LEN;

#define LOADKV(K0, K1, V0, V1, tt)                                              \
  {                                                                             \
    const unsigned short* kt_ = kb + ((size_t)(tt) * 64 + l15) * HEADD + lg * 8;\
    const unsigned short* vt_ = vb + (size_t)l15 * S_LEN + (tt) * 64 + lg * 8;  \
    _Pragma("unroll")                                                           \
    for (int nf = 0; nf < 4; nf++) {                                            \
      K0[nf] = *(const bf16x8*)(kt_ + (size_t)nf * 16 * HEADD);                 \
      K1[nf] = *(const bf16x8*)(kt_ + (size_t)nf * 16 * HEADD + 32);            \
      V0[nf] = *(const bf16x8*)(vt_ + (size_t)nf * 16 * S_LEN);                 \
      V1[nf] = *(const bf16x8*)(vt_ + (size_t)nf * 16 * S_LEN + 32);            \
    }                                                                           \
  }

#define PROCTILE(K0, K1, V0, V1, tt)                                            \
  {                                                                             \
    f32x4 sc[4];                                                                \
    _Pragma("unroll")                                                           \
    for (int nf = 0; nf < 4; nf++) {                                            \
      f32x4 z = (f32x4){0.f, 0.f, 0.f, 0.f};                                    \
      z = __builtin_amdgcn_mfma_f32_16x16x32_bf16(K0[nf], bq0, z, 0, 0, 0);     \
      sc[nf] = __builtin_amdgcn_mfma_f32_16x16x32_bf16(K1[nf], bq1, z, 0, 0, 0);\
    }                                                                           \
    if ((tt) == tl) {                                                           \
      const int qa = qbase + l15;                                               \
      _Pragma("unroll")                                                         \
      for (int nf = 0; nf < 4; nf++)                                            \
        _Pragma("unroll")                                                       \
        for (int i = 0; i < 4; i++)                                             \
          if ((tt) * 64 + nf * 16 + lg * 4 + i > qa) sc[nf][i] = -1.0e30f;      \
    }                                                                           \
    float pm = sc[0][0];                                                        \
    _Pragma("unroll")                                                           \
    for (int nf = 0; nf < 4; nf++)                                              \
      _Pragma("unroll")                                                         \
      for (int i = 0; i < 4; i++) pm = fmaxf(pm, sc[nf][i]);                    \
    if (!__all(pm <= m + 8.0f)) {                                               \
      float mx = fmaxf(pm, __shfl_xor(pm, 16));                                 \
      mx = fmaxf(mx, __shfl_xor(mx, 32));                                       \
      const float mn = fmaxf(m, mx);                                            \
      const float al = __builtin_amdgcn_exp2f(m - mn);                          \
      m = mn;                                                                   \
      l *= al;                                                                  \
      float alr[4];                                                             \
      _Pragma("unroll")                                                         \
      for (int i = 0; i < 4; i++) alr[i] = __shfl(al, lg * 4 + i);              \
      _Pragma("unroll")                                                         \
      for (int nd = 0; nd < 4; nd++)                                            \
        _Pragma("unroll")                                                       \
        for (int i = 0; i < 4; i++) o[nd][i] *= alr[i];                         \
    }                                                                           \
    _Pragma("unroll")                                                           \
    for (int nf = 0; nf < 4; nf++) {                                            \
      f32x4 p;                                                                  \
      _Pragma("unroll")                                                         \
      for (int i = 0; i < 4; i++) p[i] = __builtin_amdgcn_exp2f(sc[nf][i] - m); \
      l += p[0] + p[1] + p[2] + p[3];                                           \
      unsigned lo_ = __builtin_amdgcn_perm(fbits(p[1]) + 0x8000u,               \
                                           fbits(p[0]) + 0x8000u, 0x07060302u); \
      unsigned hi_ = __builtin_amdgcn_perm(fbits(p[3]) + 0x8000u,               \
                                           fbits(p[2]) + 0x8000u, 0x07060302u); \
      uint2 pk_; pk_.x = lo_; pk_.y = hi_;                                      \
      *(uint2*)&pl[w][l15][nf * 16 + lg * 4] = pk_;                             \
    }                                                                           \
    const bf16x8 ap0 = *(const bf16x8*)&pl[w][l15][lg * 8];                     \
    const bf16x8 ap1 = *(const bf16x8*)&pl[w][l15][32 + lg * 8];                \
    _Pragma("unroll")                                                           \
    for (int nd = 0; nd < 4; nd++) {                                            \
      f32x4 oo = __builtin_amdgcn_mfma_f32_16x16x32_bf16(ap0, V0[nd], o[nd], 0, 0, 0); \
      o[nd] = __builtin_amdgcn_mfma_f32_16x16x32_bf16(ap1, V1[nd], oo, 0, 0, 0);\
    }                                                                           \
  }

#pragma unroll 1
  for (int p = 0; p < 2; p++) {
    const int qt = p ? j2 : 255 - j2;
    const int qbase = qt * 16;
    const int tl = qt >> 2;                  // diagonal kv-tile index

    const unsigned short* qp = qws + ((size_t)b * S_LEN + qbase + l15) * HEADD + lg * 8;
    const bf16x8 bq0 = *(const bf16x8*)qp;
    const bf16x8 bq1 = *(const bf16x8*)(qp + 32);

    f32x4 o[4];
#pragma unroll
    for (int nd = 0; nd < 4; nd++) o[nd] = (f32x4){0.f, 0.f, 0.f, 0.f};
    float m = -3.0e38f, l = 0.f;

    if (w <= tl) {
      bf16x8 kA0[4], kA1[4], vA0[4], vA1[4];
      bf16x8 kB0[4], kB1[4], vB0[4], vB1[4];
      LOADKV(kA0, kA1, vA0, vA1, w);
      int t = w;
#pragma unroll 1
      while (true) {
        const int t1 = t + 4;
        const bool h1 = t1 <= tl;
        if (h1) LOADKV(kB0, kB1, vB0, vB1, t1);
        PROCTILE(kA0, kA1, vA0, vA1, t);
        if (!h1) break;
        const int t2 = t1 + 4;
        const bool h2 = t2 <= tl;
        if (h2) LOADKV(kA0, kA1, vA0, vA1, t2);
        PROCTILE(kB0, kB1, vB0, vB1, t1);
        if (!h2) break;
        t = t2;
      }
    }

    // finalize lane-partial l, publish partials
    l += __shfl_xor(l, 16);
    l += __shfl_xor(l, 32);
    if (lane < 16) { mbuf[w][lane] = m; lbuf[w][lane] = l; }
    if (w > 0) {
#pragma unroll
      for (int nd = 0; nd < 4; nd++)
#pragma unroll
        for (int i = 0; i < 4; i++) obuf[w - 1][nd][lg * 4 + i][l15] = o[nd][i];
    }
    __syncthreads();
    if (w == 0) {
#pragma unroll
      for (int i = 0; i < 4; i++) {
        const int r = lg * 4 + i;
        const float m0 = mbuf[0][r], m1 = mbuf[1][r], m2 = mbuf[2][r], m3 = mbuf[3][r];
        const float M = fmaxf(fmaxf(m0, m1), fmaxf(m2, m3));
        const float a0 = __builtin_amdgcn_exp2f(m0 - M);
        const float a1 = __builtin_amdgcn_exp2f(m1 - M);
        const float a2 = __builtin_amdgcn_exp2f(m2 - M);
        const float a3 = __builtin_amdgcn_exp2f(m3 - M);
        const float L = a0 * lbuf[0][r] + a1 * lbuf[1][r] + a2 * lbuf[2][r] + a3 * lbuf[3][r];
        const float iL = 1.0f / L;
#pragma unroll
        for (int nd = 0; nd < 4; nd++) {
          const float val = (o[nd][i] * a0 + obuf[0][nd][r][l15] * a1 +
                             obuf[1][nd][r][l15] * a2 + obuf[2][nd][r][l15] * a3) * iL;
          out[((size_t)b * S_LEN + qbase + r) * HEADD + nd * 16 + l15] = val;
        }
      }
    }
    __syncthreads();   // obuf/mbuf safe to reuse in next phase
  }
#undef LOADKV
#undef PROCTILE
}

extern "C" void kernel_launch(void* const* d_in, const int* in_sizes, int n_in,
                              void* d_out, int out_size, void* d_ws, size_t ws_size,
                              hipStream_t stream) {
  const float* X  = (const float*)d_in[0];
  const float* Wk = (const float*)d_in[1];
  const float* bk = (const float*)d_in[2];
  const float* Wq = (const float*)d_in[3];
  const float* bq = (const float*)d_in[4];
  const float* Wv = (const float*)d_in[5];
  const float* bv = (const float*)d_in[6];
  float* out = (float*)d_out;

  char* ws = (char*)d_ws;
  unsigned short* kws  = (unsigned short*)(ws);                      // 2 MB
  unsigned short* qws  = (unsigned short*)(ws + (2u << 20));         // 2 MB
  unsigned short* vtws = (unsigned short*)(ws + (4u << 20));         // 2 MB (transposed)
  unsigned short* wt   = (unsigned short*)(ws + (6u << 20));         // 384 KB
  float*          bias = (float*)(ws + (6u << 20) + (512u << 10));   // 768 B

  prep_w<<<dim3(192), dim3(256), 0, stream>>>(Wk, bk, Wq, bq, Wv, bv, wt, bias);
  proj_qkv<<<dim3(512), dim3(128), 0, stream>>>(X, wt, bias, qws, kws, vtws);
  attn<<<dim3(512), dim3(256), 0, stream>>>(qws, kws, vtws, out);
}

// Round 6
// 100.000 us; speedup vs baseline: 1.8790x; 1.2539x over previous
//
#include <hip/hip_runtime.h>

#define S_LEN 4096
#define EMBD  1024
#define HEADD 64

typedef __bf16 bf16x8 __attribute__((ext_vector_type(8)));
typedef float  f32x4  __attribute__((ext_vector_type(4)));

__device__ __forceinline__ unsigned short f2bf(float f) {
  union { float f; unsigned u; } x; x.f = f;
  unsigned r = x.u + 0x7FFFu + ((x.u >> 16) & 1u);
  return (unsigned short)(r >> 16);
}

__device__ __forceinline__ bf16x8 cvt8(f32x4 a, f32x4 b) {
  union { bf16x8 v; unsigned short s[8]; } u;
#pragma unroll
  for (int j = 0; j < 4; j++) { u.s[j] = f2bf(a[j]); u.s[4 + j] = f2bf(b[j]); }
  return u.v;
}

__device__ __forceinline__ unsigned fbits(float f) {
  union { float f; unsigned u; } x; x.f = f; return x.u;
}

// ---------------- Kernel 0: W transpose/convert + bias; fold scale*log2e into Q ----
__global__ void prep_w(const float* __restrict__ Wk, const float* __restrict__ bk,
                       const float* __restrict__ Wq, const float* __restrict__ bq,
                       const float* __restrict__ Wv, const float* __restrict__ bv,
                       unsigned short* __restrict__ wt, float* __restrict__ bias) {
  int n = blockIdx.x;            // 0..191 : [0,64)=K, [64,128)=Q(scaled), [128,192)=V
  int t = threadIdx.x;
  const float QSCALE = 0.125f * 1.44269504088896340736f;  // 1/sqrt(64) * log2(e)
  const float* W; const float* bsrc; int col; float s = 1.0f;
  if (n < 64)       { W = Wk; bsrc = bk; col = n; }
  else if (n < 128) { W = Wq; bsrc = bq; col = n - 64; s = QSCALE; }
  else              { W = Wv; bsrc = bv; col = n - 128; }
  for (int k = t; k < EMBD; k += 256)
    wt[n * EMBD + k] = f2bf(W[k * HEADD + col] * s);
  if (t == 0) bias[n] = bsrc[col] * s;
}

// ---------------- Kernel 1: QKV projection, LDS-staged X, N-split across waves -----
// 512 blocks x 256 thr (4 waves). Block = 32 rows. Stage X->bf16 in LDS (swizzled,
// conflict-free), then each wave computes 3 of 12 N-frags over full K=1024.
// X read once from HBM (64 MB); W frags are full 64B lines from L2.
__global__ __launch_bounds__(256, 2) void proj_qkv(
    const float* __restrict__ X, const unsigned short* __restrict__ wt,
    const float* __restrict__ bias,
    unsigned short* __restrict__ qws, unsigned short* __restrict__ kws,
    unsigned short* __restrict__ vtws) {
  __shared__ unsigned short xs[32 * 1024];   // 64 KB, XOR-swizzled 16B slots

  const int tid = threadIdx.x;
  const int w = tid >> 6;
  const int lane = tid & 63;
  const int l15 = lane & 15, lg = lane >> 4;
  const int row0 = blockIdx.x * 32;

  // ---- stage X (f32 HBM, coalesced) -> LDS bf16, swizzled ----
#pragma unroll
  for (int it = 0; it < 16; it++) {
    const int u = it * 256 + tid;            // 0..4095
    const int r = u >> 7;                    // 0..31
    const int c = (u & 127) * 8;             // 0..1016
    const f32x4 a  = *(const f32x4*)(X + (size_t)(row0 + r) * EMBD + c);
    const f32x4 b2 = *(const f32x4*)(X + (size_t)(row0 + r) * EMBD + c + 4);
    int soff = (r << 10) + c;
    soff ^= (r & 7) << 3;                    // 16B-slot XOR swizzle
    *(bf16x8*)&xs[soff] = cvt8(a, b2);
  }
  __syncthreads();

  // ---- compute: wave w owns N-frags w*3 .. w*3+2, rows rg=0,1 ----
  f32x4 acc[2][3];
#pragma unroll
  for (int rg = 0; rg < 2; rg++)
#pragma unroll
    for (int j = 0; j < 3; j++) acc[rg][j] = (f32x4){0.f, 0.f, 0.f, 0.f};

  const unsigned short* wp = wt + (size_t)(w * 48 + l15) * EMBD + lg * 8;

#pragma unroll 4
  for (int s = 0; s < 32; s++) {
    const int c = s * 32 + lg * 8;
    int so0 = (l15 << 10) + c;        so0 ^= (l15 & 7) << 3;
    int so1 = ((16 + l15) << 10) + c; so1 ^= (l15 & 7) << 3;
    const bf16x8 a0 = *(const bf16x8*)&xs[so0];
    const bf16x8 a1 = *(const bf16x8*)&xs[so1];
#pragma unroll
    for (int j = 0; j < 3; j++) {
      const bf16x8 bf = *(const bf16x8*)(wp + (size_t)j * 16 * EMBD + s * 32);
      acc[0][j] = __builtin_amdgcn_mfma_f32_16x16x32_bf16(a0, bf, acc[0][j], 0, 0, 0);
      acc[1][j] = __builtin_amdgcn_mfma_f32_16x16x32_bf16(a1, bf, acc[1][j], 0, 0, 0);
    }
  }

  // ---- epilogue ----
#pragma unroll
  for (int rg = 0; rg < 2; rg++) {
    const int crow0 = row0 + rg * 16 + lg * 4;
#pragma unroll
    for (int j = 0; j < 3; j++) {
      const int nf = w * 3 + j;
      const int n = nf * 16 + l15;
      const float bs = bias[n];
      if (nf < 8) {
        unsigned short* dst = (nf < 4) ? kws : qws;
        const int nn = n & 63;
#pragma unroll
        for (int i = 0; i < 4; i++)
          dst[(size_t)(crow0 + i) * HEADD + nn] = f2bf(acc[rg][j][i] + bs);
      } else {
        const int d = n - 128;
        const int bb = crow0 >> 12, sr = crow0 & 4095;
        union { unsigned long long pk; unsigned short s[4]; } u;
#pragma unroll
        for (int i = 0; i < 4; i++) u.s[i] = f2bf(acc[rg][j][i] + bs);
        *(unsigned long long*)&vtws[((size_t)bb * HEADD + d) * S_LEN + sr] = u.pk;
      }
    }
  }
}

// ---------------- Kernel 2: causal flash attention ---------------------------------
// 512 blocks x 256 thr (4 waves, kv-split-4). Each WAVE carries TWO q-groups
// (heavy gH = 255-pair, light gL = pair): every loaded K/V tile feeds 32 q-rows
// -> L2 traffic halved, uniform work per block, H/L chains give 2x ILP per load.
// Batch pinned to XCD pairs via blockIdx&7 for L2 residency.
__global__ __launch_bounds__(256, 2) void attn(
    const unsigned short* __restrict__ qws,
    const unsigned short* __restrict__ kws,
    const unsigned short* __restrict__ vtws,
    float* __restrict__ out) {
  __shared__ unsigned short pl[4][16][72];   // per-wave P bounce (wave-private)
  __shared__ float obuf[3][4][16][17];       // partials from waves 1..3
  __shared__ float mbuf[4][16], lbuf[4][16];

  const int w = threadIdx.x >> 6;
  const int lane = threadIdx.x & 63;
  const int l15 = lane & 15, lg = lane >> 4;

  const int xslot = blockIdx.x & 7;          // ~XCD id (round-robin heuristic)
  const int b = xslot >> 1;                  // batch pinned to 2 XCDs
  const int pair = ((xslot & 1) << 6) | (blockIdx.x >> 3);   // 0..127
  const int gH = 255 - pair, gL = pair;
  const int qbH = gH << 4, qbL = gL << 4;
  const int tlH = gH >> 2, tlL = gL >> 2;    // diagonal tiles (tlL < tlH always)

  const unsigned short* kb = kws + (size_t)b * S_LEN * HEADD;
  const unsigned short* vb = vtws + (size_t)b * HEADD * S_LEN;

  const unsigned short* qpH = qws + ((size_t)b * S_LEN + qbH + l15) * HEADD + lg * 8;
  const bf16x8 bqH0 = *(const bf16x8*)qpH;
  const bf16x8 bqH1 = *(const bf16x8*)(qpH + 32);
  const unsigned short* qpL = qws + ((size_t)b * S_LEN + qbL + l15) * HEADD + lg * 8;
  const bf16x8 bqL0 = *(const bf16x8*)qpL;
  const bf16x8 bqL1 = *(const bf16x8*)(qpL + 32);

  f32x4 oH[4], oL[4];
#pragma unroll
  for (int nd = 0; nd < 4; nd++) {
    oH[nd] = (f32x4){0.f, 0.f, 0.f, 0.f};
    oL[nd] = (f32x4){0.f, 0.f, 0.f, 0.f};
  }
  float mH = -3.0e38f, lH = 0.f, mL = -3.0e38f, lL = 0.f;

#define PROC(BQ0, BQ1, O, M, LL, QB, TLX, tt)                                   \
  do {                                                                          \
    f32x4 sc[4];                                                                \
    __builtin_amdgcn_s_setprio(1);                                              \
    _Pragma("unroll")                                                           \
    for (int nf = 0; nf < 4; nf++) {                                            \
      f32x4 z = (f32x4){0.f, 0.f, 0.f, 0.f};                                    \
      z = __builtin_amdgcn_mfma_f32_16x16x32_bf16(k0[nf], BQ0, z, 0, 0, 0);     \
      sc[nf] = __builtin_amdgcn_mfma_f32_16x16x32_bf16(k1[nf], BQ1, z, 0, 0, 0);\
    }                                                                           \
    __builtin_amdgcn_s_setprio(0);                                              \
    if ((tt) == (TLX)) {                                                        \
      const int qa = (QB) + l15;                                                \
      _Pragma("unroll")                                                         \
      for (int nf = 0; nf < 4; nf++)                                            \
        _Pragma("unroll")                                                       \
        for (int i = 0; i < 4; i++)                                             \
          if ((tt) * 64 + nf * 16 + lg * 4 + i > qa) sc[nf][i] = -1.0e30f;      \
    }                                                                           \
    float pm = sc[0][0];                                                        \
    _Pragma("unroll")                                                           \
    for (int nf = 0; nf < 4; nf++)                                              \
      _Pragma("unroll")                                                         \
      for (int i = 0; i < 4; i++) pm = fmaxf(pm, sc[nf][i]);                    \
    if (!__all(pm <= M + 8.0f)) {                                               \
      float mx = fmaxf(pm, __shfl_xor(pm, 16));                                 \
      mx = fmaxf(mx, __shfl_xor(mx, 32));                                       \
      const float mn = fmaxf(M, mx);                                            \
      const float al = __builtin_amdgcn_exp2f(M - mn);                          \
      M = mn;                                                                   \
      LL *= al;                                                                 \
      float alr[4];                                                             \
      _Pragma("unroll")                                                         \
      for (int i = 0; i < 4; i++) alr[i] = __shfl(al, lg * 4 + i);              \
      _Pragma("unroll")                                                         \
      for (int nd = 0; nd < 4; nd++)                                            \
        _Pragma("unroll")                                                       \
        for (int i = 0; i < 4; i++) O[nd][i] *= alr[i];                         \
    }                                                                           \
    _Pragma("unroll")                                                           \
    for (int nf = 0; nf < 4; nf++) {                                            \
      f32x4 p;                                                                  \
      _Pragma("unroll")                                                         \
      for (int i = 0; i < 4; i++) p[i] = __builtin_amdgcn_exp2f(sc[nf][i] - M); \
      LL += p[0] + p[1] + p[2] + p[3];                                          \
      unsigned lo_ = __builtin_amdgcn_perm(fbits(p[1]) + 0x8000u,               \
                                           fbits(p[0]) + 0x8000u, 0x07060302u); \
      unsigned hi_ = __builtin_amdgcn_perm(fbits(p[3]) + 0x8000u,               \
                                           fbits(p[2]) + 0x8000u, 0x07060302u); \
      uint2 pk_; pk_.x = lo_; pk_.y = hi_;                                      \
      *(uint2*)&pl[w][l15][nf * 16 + lg * 4] = pk_;                             \
    }                                                                           \
    const bf16x8 ap0 = *(const bf16x8*)&pl[w][l15][lg * 8];                     \
    const bf16x8 ap1 = *(const bf16x8*)&pl[w][l15][32 + lg * 8];                \
    __builtin_amdgcn_s_setprio(1);                                              \
    _Pragma("unroll")                                                           \
    for (int nd = 0; nd < 4; nd++) {                                            \
      f32x4 oo = __builtin_amdgcn_mfma_f32_16x16x32_bf16(ap0, v0[nd], O[nd], 0, 0, 0); \
      O[nd] = __builtin_amdgcn_mfma_f32_16x16x32_bf16(ap1, v1[nd], oo, 0, 0, 0);\
    }                                                                           \
    __builtin_amdgcn_s_setprio(0);                                              \
  } while (0)

#pragma unroll 1
  for (int t = w; t <= tlH; t += 4) {
    bf16x8 k0[4], k1[4], v0[4], v1[4];
    {
      const unsigned short* kt = kb + ((size_t)t * 64 + l15) * HEADD + lg * 8;
      const unsigned short* vt = vb + (size_t)l15 * S_LEN + t * 64 + lg * 8;
#pragma unroll
      for (int nf = 0; nf < 4; nf++) {
        k0[nf] = *(const bf16x8*)(kt + (size_t)nf * 16 * HEADD);
        k1[nf] = *(const bf16x8*)(kt + (size_t)nf * 16 * HEADD + 32);
        v0[nf] = *(const bf16x8*)(vt + (size_t)nf * 16 * S_LEN);
        v1[nf] = *(const bf16x8*)(vt + (size_t)nf * 16 * S_LEN + 32);
      }
    }
    PROC(bqH0, bqH1, oH, mH, lH, qbH, tlH, t);
    if (t <= tlL) PROC(bqL0, bqL1, oL, mL, lL, qbL, tlL, t);
  }
#undef PROC

  // ---- merge 4 kv-splits per group (H then L, reusing buffers) ----
#define MERGE(O, M, LL, QB)                                                     \
  do {                                                                          \
    LL += __shfl_xor(LL, 16);                                                   \
    LL += __shfl_xor(LL, 32);                                                   \
    if (lane < 16) { mbuf[w][lane] = M; lbuf[w][lane] = LL; }                   \
    if (w > 0) {                                                                \
      _Pragma("unroll")                                                         \
      for (int nd = 0; nd < 4; nd++)                                            \
        _Pragma("unroll")                                                       \
        for (int i = 0; i < 4; i++) obuf[w - 1][nd][lg * 4 + i][l15] = O[nd][i];\
    }                                                                           \
    __syncthreads();                                                            \
    if (w == 0) {                                                               \
      _Pragma("unroll")                                                         \
      for (int i = 0; i < 4; i++) {                                             \
        const int r = lg * 4 + i;                                               \
        const float m0 = mbuf[0][r], m1 = mbuf[1][r];                           \
        const float m2 = mbuf[2][r], m3 = mbuf[3][r];                           \
        const float M4 = fmaxf(fmaxf(m0, m1), fmaxf(m2, m3));                   \
        const float a0 = __builtin_amdgcn_exp2f(m0 - M4);                       \
        const float a1 = __builtin_amdgcn_exp2f(m1 - M4);                       \
        const float a2 = __builtin_amdgcn_exp2f(m2 - M4);                       \
        const float a3 = __builtin_amdgcn_exp2f(m3 - M4);                       \
        const float Lt = a0 * lbuf[0][r] + a1 * lbuf[1][r] +                    \
                         a2 * lbuf[2][r] + a3 * lbuf[3][r];                     \
        const float iL = 1.0f / Lt;                                             \
        _Pragma("unroll")                                                       \
        for (int nd = 0; nd < 4; nd++) {                                        \
          const float val = (O[nd][i] * a0 + obuf[0][nd][r][l15] * a1 +         \
                             obuf[1][nd][r][l15] * a2 +                         \
                             obuf[2][nd][r][l15] * a3) * iL;                    \
          out[((size_t)b * S_LEN + (QB) + r) * HEADD + nd * 16 + l15] = val;    \
        }                                                                       \
      }                                                                         \
    }                                                                           \
    __syncthreads();                                                            \
  } while (0)

  MERGE(oH, mH, lH, qbH);
  MERGE(oL, mL, lL, qbL);
#undef MERGE
}

extern "C" void kernel_launch(void* const* d_in, const int* in_sizes, int n_in,
                              void* d_out, int out_size, void* d_ws, size_t ws_size,
                              hipStream_t stream) {
  const float* X  = (const float*)d_in[0];
  const float* Wk = (const float*)d_in[1];
  const float* bk = (const float*)d_in[2];
  const float* Wq = (const float*)d_in[3];
  const float* bq = (const float*)d_in[4];
  const float* Wv = (const float*)d_in[5];
  const float* bv = (const float*)d_in[6];
  float* out = (float*)d_out;

  char* ws = (char*)d_ws;
  unsigned short* kws  = (unsigned short*)(ws);                      // 2 MB
  unsigned short* qws  = (unsigned short*)(ws + (2u << 20));         // 2 MB
  unsigned short* vtws = (unsigned short*)(ws + (4u << 20));         // 2 MB (transposed)
  unsigned short* wt   = (unsigned short*)(ws + (6u << 20));         // 384 KB
  float*          bias = (float*)(ws + (6u << 20) + (512u << 10));   // 768 B

  prep_w<<<dim3(192), dim3(256), 0, stream>>>(Wk, bk, Wq, bq, Wv, bv, wt, bias);
  proj_qkv<<<dim3(512), dim3(256), 0, stream>>>(X, wt, bias, qws, kws, vtws);
  attn<<<dim3(512), dim3(256), 0, stream>>>(qws, kws, vtws, out);
}

// Round 7
// 82.199 us; speedup vs baseline: 2.2859x; 1.2166x over previous
//
#include <hip/hip_runtime.h>

#define S_LEN 4096
#define EMBD  1024
#define HEADD 64

typedef __bf16 bf16x8 __attribute__((ext_vector_type(8)));
typedef float  f32x4  __attribute__((ext_vector_type(4)));

__device__ __forceinline__ unsigned short f2bf(float f) {
  union { float f; unsigned u; } x; x.f = f;
  unsigned r = x.u + 0x7FFFu + ((x.u >> 16) & 1u);
  return (unsigned short)(r >> 16);
}

__device__ __forceinline__ bf16x8 cvt8(f32x4 a, f32x4 b) {
  union { bf16x8 v; unsigned short s[8]; } u;
#pragma unroll
  for (int j = 0; j < 4; j++) { u.s[j] = f2bf(a[j]); u.s[4 + j] = f2bf(b[j]); }
  return u.v;
}

__device__ __forceinline__ unsigned fbits(float f) {
  union { float f; unsigned u; } x; x.f = f; return x.u;
}

// ---------------- Kernel 0: W transpose/convert + bias; fold scale*log2e into Q ----
__global__ void prep_w(const float* __restrict__ Wk, const float* __restrict__ bk,
                       const float* __restrict__ Wq, const float* __restrict__ bq,
                       const float* __restrict__ Wv, const float* __restrict__ bv,
                       unsigned short* __restrict__ wt, float* __restrict__ bias) {
  int n = blockIdx.x;            // 0..191 : [0,64)=K, [64,128)=Q(scaled), [128,192)=V
  int t = threadIdx.x;
  const float QSCALE = 0.125f * 1.44269504088896340736f;  // 1/sqrt(64) * log2(e)
  const float* W; const float* bsrc; int col; float s = 1.0f;
  if (n < 64)       { W = Wk; bsrc = bk; col = n; }
  else if (n < 128) { W = Wq; bsrc = bq; col = n - 64; s = QSCALE; }
  else              { W = Wv; bsrc = bv; col = n - 128; }
  for (int k = t; k < EMBD; k += 256)
    wt[n * EMBD + k] = f2bf(W[k * HEADD + col] * s);
  if (t == 0) bias[n] = bsrc[col] * s;
}

// ---------------- Kernel 1: QKV projection, LDS-staged X, N-split across waves -----
// 512 blocks x 256 thr (4 waves). Block = 32 rows. Stage: batched loads (4x MLP)
// then convert/write. Compute: W-frags ping-ponged one K-step ahead (wfA/wfB).
__global__ __launch_bounds__(256, 2) void proj_qkv(
    const float* __restrict__ X, const unsigned short* __restrict__ wt,
    const float* __restrict__ bias,
    unsigned short* __restrict__ qws, unsigned short* __restrict__ kws,
    unsigned short* __restrict__ vtws) {
  __shared__ unsigned short xs[32 * 1024];   // 64 KB, XOR-swizzled 16B slots

  const int tid = threadIdx.x;
  const int w = tid >> 6;
  const int lane = tid & 63;
  const int l15 = lane & 15, lg = lane >> 4;
  const int row0 = blockIdx.x * 32;

  // ---- stage X (f32 HBM) -> LDS bf16: 4 chunks of {8 loads, then 4 writes} ----
#pragma unroll
  for (int c4 = 0; c4 < 16; c4 += 4) {
    f32x4 la[4], lb[4];
#pragma unroll
    for (int j = 0; j < 4; j++) {
      const int u = (c4 + j) * 256 + tid;
      const int r = u >> 7, c = (u & 127) * 8;
      la[j] = *(const f32x4*)(X + (size_t)(row0 + r) * EMBD + c);
      lb[j] = *(const f32x4*)(X + (size_t)(row0 + r) * EMBD + c + 4);
    }
#pragma unroll
    for (int j = 0; j < 4; j++) {
      const int u = (c4 + j) * 256 + tid;
      const int r = u >> 7, c = (u & 127) * 8;
      int soff = (r << 10) + c;
      soff ^= (r & 7) << 3;                  // 16B-slot XOR swizzle
      *(bf16x8*)&xs[soff] = cvt8(la[j], lb[j]);
    }
  }
  __syncthreads();

  // ---- compute: wave w owns N-frags w*3 .. w*3+2, rows rg=0,1; W ping-pong ----
  f32x4 acc[2][3];
#pragma unroll
  for (int rg = 0; rg < 2; rg++)
#pragma unroll
    for (int j = 0; j < 3; j++) acc[rg][j] = (f32x4){0.f, 0.f, 0.f, 0.f};

  const unsigned short* wp = wt + (size_t)(w * 48 + l15) * EMBD + lg * 8;

  bf16x8 wfA[3], wfB[3];
#pragma unroll
  for (int j = 0; j < 3; j++) wfA[j] = *(const bf16x8*)(wp + (size_t)j * 16 * EMBD);

#pragma unroll
  for (int s = 0; s < 32; s += 2) {
#pragma unroll
    for (int j = 0; j < 3; j++)
      wfB[j] = *(const bf16x8*)(wp + (size_t)j * 16 * EMBD + (s + 1) * 32);
    {
      const int c = s * 32 + lg * 8;
      int so0 = (l15 << 10) + c;        so0 ^= (l15 & 7) << 3;
      int so1 = ((16 + l15) << 10) + c; so1 ^= (l15 & 7) << 3;
      const bf16x8 a0 = *(const bf16x8*)&xs[so0];
      const bf16x8 a1 = *(const bf16x8*)&xs[so1];
#pragma unroll
      for (int j = 0; j < 3; j++) {
        acc[0][j] = __builtin_amdgcn_mfma_f32_16x16x32_bf16(a0, wfA[j], acc[0][j], 0, 0, 0);
        acc[1][j] = __builtin_amdgcn_mfma_f32_16x16x32_bf16(a1, wfA[j], acc[1][j], 0, 0, 0);
      }
    }
    if (s + 2 < 32) {
#pragma unroll
      for (int j = 0; j < 3; j++)
        wfA[j] = *(const bf16x8*)(wp + (size_t)j * 16 * EMBD + (s + 2) * 32);
    }
    {
      const int c = (s + 1) * 32 + lg * 8;
      int so0 = (l15 << 10) + c;        so0 ^= (l15 & 7) << 3;
      int so1 = ((16 + l15) << 10) + c; so1 ^= (l15 & 7) << 3;
      const bf16x8 a0 = *(const bf16x8*)&xs[so0];
      const bf16x8 a1 = *(const bf16x8*)&xs[so1];
#pragma unroll
      for (int j = 0; j < 3; j++) {
        acc[0][j] = __builtin_amdgcn_mfma_f32_16x16x32_bf16(a0, wfB[j], acc[0][j], 0, 0, 0);
        acc[1][j] = __builtin_amdgcn_mfma_f32_16x16x32_bf16(a1, wfB[j], acc[1][j], 0, 0, 0);
      }
    }
  }

  // ---- epilogue ----
#pragma unroll
  for (int rg = 0; rg < 2; rg++) {
    const int crow0 = row0 + rg * 16 + lg * 4;
#pragma unroll
    for (int j = 0; j < 3; j++) {
      const int nf = w * 3 + j;
      const int n = nf * 16 + l15;
      const float bs = bias[n];
      if (nf < 8) {
        unsigned short* dst = (nf < 4) ? kws : qws;
        const int nn = n & 63;
#pragma unroll
        for (int i = 0; i < 4; i++)
          dst[(size_t)(crow0 + i) * HEADD + nn] = f2bf(acc[rg][j][i] + bs);
      } else {
        const int d = n - 128;
        const int bb = crow0 >> 12, sr = crow0 & 4095;
        union { unsigned long long pk; unsigned short s[4]; } u;
#pragma unroll
        for (int i = 0; i < 4; i++) u.s[i] = f2bf(acc[rg][j][i] + bs);
        *(unsigned long long*)&vtws[((size_t)bb * HEADD + d) * S_LEN + sr] = u.pk;
      }
    }
  }
}

// ---------------- Kernel 2: causal flash attention ---------------------------------
// 256 blocks x 512 thr (8 waves, kv-split-8), exactly 1 block/CU, uniform work.
// Each WAVE carries FOUR 16-row q-groups: heavy pair (pH=127-x: rows qbH..qbH+31)
// + light pair (pL=x). tlH+tlL=63 -> every block = 65 tile-units. Each 16 KB K/V
// tile load feeds 2-4 PROCs (64 q-rows) -> L2 traffic ~200 MB total. K/V regs are
// live across all PROCs so loads cannot be sunk into a serial chain.
__global__ __launch_bounds__(512, 2) void attn(
    const unsigned short* __restrict__ qws,
    const unsigned short* __restrict__ kws,
    const unsigned short* __restrict__ vtws,
    float* __restrict__ out) {
  __shared__ unsigned short pl[8][16][72];   // per-wave P bounce (wave-private)
  __shared__ float obuf[7][4][16][17];       // partials from waves 1..7 (per group)
  __shared__ float mbuf[8][16], lbuf[8][16];

  const int w = threadIdx.x >> 6;
  const int lane = threadIdx.x & 63;
  const int l15 = lane & 15, lg = lane >> 4;

  const int b = blockIdx.x & 3;              // batch -> XCDs {b, b+4}
  const int x = blockIdx.x >> 2;             // 0..63
  const int pH = 127 - x, pL = x;
  const int qbH = pH << 5, qbL = pL << 5;
  const int tlH = pH >> 1, tlL = pL >> 1;    // diagonal kv-tiles (tlL < tlH)

  const unsigned short* kb = kws + (size_t)b * S_LEN * HEADD;
  const unsigned short* vb = vtws + (size_t)b * HEADD * S_LEN;
  const unsigned short* qp = qws + (size_t)b * S_LEN * HEADD;

  const unsigned short* qA = qp + (size_t)(qbH + l15) * HEADD + lg * 8;
  const unsigned short* qB = qp + (size_t)(qbH + 16 + l15) * HEADD + lg * 8;
  const unsigned short* qC = qp + (size_t)(qbL + l15) * HEADD + lg * 8;
  const unsigned short* qD = qp + (size_t)(qbL + 16 + l15) * HEADD + lg * 8;
  const bf16x8 bqA0 = *(const bf16x8*)qA, bqA1 = *(const bf16x8*)(qA + 32);
  const bf16x8 bqB0 = *(const bf16x8*)qB, bqB1 = *(const bf16x8*)(qB + 32);
  const bf16x8 bqC0 = *(const bf16x8*)qC, bqC1 = *(const bf16x8*)(qC + 32);
  const bf16x8 bqD0 = *(const bf16x8*)qD, bqD1 = *(const bf16x8*)(qD + 32);

  f32x4 oA[4], oB[4], oC[4], oD[4];
#pragma unroll
  for (int nd = 0; nd < 4; nd++) {
    oA[nd] = (f32x4){0.f, 0.f, 0.f, 0.f};
    oB[nd] = (f32x4){0.f, 0.f, 0.f, 0.f};
    oC[nd] = (f32x4){0.f, 0.f, 0.f, 0.f};
    oD[nd] = (f32x4){0.f, 0.f, 0.f, 0.f};
  }
  float mA = -3.0e38f, lA = 0.f, mB = -3.0e38f, lB = 0.f;
  float mC = -3.0e38f, lC = 0.f, mD = -3.0e38f, lD = 0.f;

#define PROC(BQ0, BQ1, O, M, LL, QB, TLX, tt)                                   \
  do {                                                                          \
    f32x4 sc[4];                                                                \
    __builtin_amdgcn_s_setprio(1);                                              \
    _Pragma("unroll")                                                           \
    for (int nf = 0; nf < 4; nf++) {                                            \
      f32x4 z = (f32x4){0.f, 0.f, 0.f, 0.f};                                    \
      z = __builtin_amdgcn_mfma_f32_16x16x32_bf16(k0[nf], BQ0, z, 0, 0, 0);     \
      sc[nf] = __builtin_amdgcn_mfma_f32_16x16x32_bf16(k1[nf], BQ1, z, 0, 0, 0);\
    }                                                                           \
    __builtin_amdgcn_s_setprio(0);                                              \
    if ((tt) == (TLX)) {                                                        \
      const int qa = (QB) + l15;                                                \
      _Pragma("unroll")                                                         \
      for (int nf = 0; nf < 4; nf++)                                            \
        _Pragma("unroll")                                                       \
        for (int i = 0; i < 4; i++)                                             \
          if ((tt) * 64 + nf * 16 + lg * 4 + i > qa) sc[nf][i] = -1.0e30f;      \
    }                                                                           \
    float pm = sc[0][0];                                                        \
    _Pragma("unroll")                                                           \
    for (int nf = 0; nf < 4; nf++)                                              \
      _Pragma("unroll")                                                         \
      for (int i = 0; i < 4; i++) pm = fmaxf(pm, sc[nf][i]);                    \
    if (!__all(pm <= M + 8.0f)) {                                               \
      float mx = fmaxf(pm, __shfl_xor(pm, 16));                                 \
      mx = fmaxf(mx, __shfl_xor(mx, 32));                                       \
      const float mn = fmaxf(M, mx);                                            \
      const float al = __builtin_amdgcn_exp2f(M - mn);                          \
      M = mn;                                                                   \
      LL *= al;                                                                 \
      float alr[4];                                                             \
      _Pragma("unroll")                                                         \
      for (int i = 0; i < 4; i++) alr[i] = __shfl(al, lg * 4 + i);              \
      _Pragma("unroll")                                                         \
      for (int nd = 0; nd < 4; nd++)                                            \
        _Pragma("unroll")                                                       \
        for (int i = 0; i < 4; i++) O[nd][i] *= alr[i];                         \
    }                                                                           \
    _Pragma("unroll")                                                           \
    for (int nf = 0; nf < 4; nf++) {                                            \
      f32x4 p;                                                                  \
      _Pragma("unroll")                                                         \
      for (int i = 0; i < 4; i++) p[i] = __builtin_amdgcn_exp2f(sc[nf][i] - M); \
      LL += p[0] + p[1] + p[2] + p[3];                                          \
      unsigned lo_ = __builtin_amdgcn_perm(fbits(p[1]) + 0x8000u,               \
                                           fbits(p[0]) + 0x8000u, 0x07060302u); \
      unsigned hi_ = __builtin_amdgcn_perm(fbits(p[3]) + 0x8000u,               \
                                           fbits(p[2]) + 0x8000u, 0x07060302u); \
      uint2 pk_; pk_.x = lo_; pk_.y = hi_;                                      \
      *(uint2*)&pl[w][l15][nf * 16 + lg * 4] = pk_;                             \
    }                                                                           \
    const bf16x8 ap0 = *(const bf16x8*)&pl[w][l15][lg * 8];                     \
    const bf16x8 ap1 = *(const bf16x8*)&pl[w][l15][32 + lg * 8];                \
    __builtin_amdgcn_s_setprio(1);                                              \
    _Pragma("unroll")                                                           \
    for (int nd = 0; nd < 4; nd++) {                                            \
      f32x4 oo = __builtin_amdgcn_mfma_f32_16x16x32_bf16(ap0, v0[nd], O[nd], 0, 0, 0); \
      O[nd] = __builtin_amdgcn_mfma_f32_16x16x32_bf16(ap1, v1[nd], oo, 0, 0, 0);\
    }                                                                           \
    __builtin_amdgcn_s_setprio(0);                                              \
  } while (0)

#pragma unroll 1
  for (int t = w; t <= tlH; t += 8) {
    bf16x8 k0[4], k1[4], v0[4], v1[4];
    {
      const unsigned short* kt = kb + ((size_t)t * 64 + l15) * HEADD + lg * 8;
      const unsigned short* vt = vb + (size_t)l15 * S_LEN + t * 64 + lg * 8;
#pragma unroll
      for (int nf = 0; nf < 4; nf++) {
        k0[nf] = *(const bf16x8*)(kt + (size_t)nf * 16 * HEADD);
        k1[nf] = *(const bf16x8*)(kt + (size_t)nf * 16 * HEADD + 32);
        v0[nf] = *(const bf16x8*)(vt + (size_t)nf * 16 * S_LEN);
        v1[nf] = *(const bf16x8*)(vt + (size_t)nf * 16 * S_LEN + 32);
      }
    }
    PROC(bqA0, bqA1, oA, mA, lA, qbH, tlH, t);
    PROC(bqB0, bqB1, oB, mB, lB, qbH + 16, tlH, t);
    if (t <= tlL) {
      PROC(bqC0, bqC1, oC, mC, lC, qbL, tlL, t);
      PROC(bqD0, bqD1, oD, mD, lD, qbL + 16, tlL, t);
    }
  }
#undef PROC

  // ---- merge the 8 kv-splits, one group at a time (obuf reused) ----
#define MERGEG(O, M, LL, QB)                                                    \
  do {                                                                          \
    LL += __shfl_xor(LL, 16);                                                   \
    LL += __shfl_xor(LL, 32);                                                   \
    if (lane < 16) { mbuf[w][lane] = M; lbuf[w][lane] = LL; }                   \
    if (w > 0) {                                                                \
      _Pragma("unroll")                                                         \
      for (int nd = 0; nd < 4; nd++)                                            \
        _Pragma("unroll")                                                       \
        for (int i = 0; i < 4; i++) obuf[w - 1][nd][lg * 4 + i][l15] = O[nd][i];\
    }                                                                           \
    __syncthreads();                                                            \
    if (w == 0) {                                                               \
      _Pragma("unroll")                                                         \
      for (int i = 0; i < 4; i++) {                                             \
        const int r = lg * 4 + i;                                               \
        float M8 = mbuf[0][r];                                                  \
        _Pragma("unroll")                                                       \
        for (int k = 1; k < 8; k++) M8 = fmaxf(M8, mbuf[k][r]);                 \
        float a[8], Lt = 0.f;                                                   \
        _Pragma("unroll")                                                       \
        for (int k = 0; k < 8; k++) {                                           \
          a[k] = __builtin_amdgcn_exp2f(mbuf[k][r] - M8);                       \
          Lt += a[k] * lbuf[k][r];                                              \
        }                                                                       \
        const float iL = 1.0f / Lt;                                             \
        _Pragma("unroll")                                                       \
        for (int nd = 0; nd < 4; nd++) {                                        \
          float val = O[nd][i] * a[0];                                          \
          _Pragma("unroll")                                                     \
          for (int k = 1; k < 8; k++) val += obuf[k - 1][nd][r][l15] * a[k];    \
          out[((size_t)b * S_LEN + (QB) + r) * HEADD + nd * 16 + l15] = val * iL; \
        }                                                                       \
      }                                                                         \
    }                                                                           \
    __syncthreads();                                                            \
  } while (0)

  MERGEG(oA, mA, lA, qbH);
  MERGEG(oB, mB, lB, qbH + 16);
  MERGEG(oC, mC, lC, qbL);
  MERGEG(oD, mD, lD, qbL + 16);
#undef MERGEG
}

extern "C" void kernel_launch(void* const* d_in, const int* in_sizes, int n_in,
                              void* d_out, int out_size, void* d_ws, size_t ws_size,
                              hipStream_t stream) {
  const float* X  = (const float*)d_in[0];
  const float* Wk = (const float*)d_in[1];
  const float* bk = (const float*)d_in[2];
  const float* Wq = (const float*)d_in[3];
  const float* bq = (const float*)d_in[4];
  const float* Wv = (const float*)d_in[5];
  const float* bv = (const float*)d_in[6];
  float* out = (float*)d_out;

  char* ws = (char*)d_ws;
  unsigned short* kws  = (unsigned short*)(ws);                      // 2 MB
  unsigned short* qws  = (unsigned short*)(ws + (2u << 20));         // 2 MB
  unsigned short* vtws = (unsigned short*)(ws + (4u << 20));         // 2 MB (transposed)
  unsigned short* wt   = (unsigned short*)(ws + (6u << 20));         // 384 KB
  float*          bias = (float*)(ws + (6u << 20) + (512u << 10));   // 768 B

  prep_w<<<dim3(192), dim3(256), 0, stream>>>(Wk, bk, Wq, bq, Wv, bv, wt, bias);
  proj_qkv<<<dim3(512), dim3(256), 0, stream>>>(X, wt, bias, qws, kws, vtws);
  attn<<<dim3(256), dim3(512), 0, stream>>>(qws, kws, vtws, out);
}